// Round 14
// baseline (168.189 us; speedup 1.0000x reference)
//
#include <hip/hip_runtime.h>
#include <math.h>

#define NN 20000
#define RR 32
#define HH 64
#define CC 8
#define EE 640000
#define CAP 128   // bucket capacity per dst node; Poisson(32) max-degree ~57
#define RT 8      // relations per k_hrel block

// ---------------------------------------------------------------- bucket build
__global__ __launch_bounds__(256) void k_zero(int* __restrict__ cnt) {
    int i = blockIdx.x * 256 + threadIdx.x;
    if (i < NN) cnt[i] = 0;
}

// 4 edges per thread, int4 loads (EE % 4 == 0). Slot via atomic bump of cnt.
__global__ __launch_bounds__(256) void k_scatter(const int* __restrict__ ei,
                                                 const int* __restrict__ et,
                                                 int* __restrict__ cnt,
                                                 unsigned* __restrict__ pk2) {
    int e = (blockIdx.x * 256 + threadIdx.x) * 4;
    if (e >= EE) return;
    int4 sv = *(const int4*)(ei + e);
    int4 dv = *(const int4*)(ei + EE + e);
    int4 rv = *(const int4*)(et + e);
    int s;
    s = atomicAdd(&cnt[dv.x], 1); pk2[((size_t)dv.x << 7) + s] = (unsigned)sv.x | ((unsigned)rv.x << 15);
    s = atomicAdd(&cnt[dv.y], 1); pk2[((size_t)dv.y << 7) + s] = (unsigned)sv.y | ((unsigned)rv.y << 15);
    s = atomicAdd(&cnt[dv.z], 1); pk2[((size_t)dv.z << 7) + s] = (unsigned)sv.z | ((unsigned)rv.z << 15);
    s = atomicAdd(&cnt[dv.w], 1); pk2[((size_t)dv.w << 7) + s] = (unsigned)sv.w | ((unsigned)rv.w << 15);
}

// ---------------------------------------------------------------- layer 1
// (round-10 form, unchanged) wave per dst node; 16-lane x float4 per W1 row.
__global__ __launch_bounds__(256) void k_gather1(const unsigned* __restrict__ pk2,
                                                 const int* __restrict__ cnt,
                                                 const float* __restrict__ W1,
                                                 const float* __restrict__ root1,
                                                 const float* __restrict__ bias1,
                                                 const float* __restrict__ root2,
                                                 float* __restrict__ h,
                                                 float* __restrict__ outr) {
    int wid = (blockIdx.x * 256 + threadIdx.x) >> 6;
    int lane = threadIdx.x & 63;
    if (wid >= NN) return;
    const int eg = lane >> 4;   // which of 4 edges in a load-group
    const int q  = lane & 15;   // float4 index within the 64-float row
    float4 acc4 = make_float4(0.f, 0.f, 0.f, 0.f);
    int beg = wid << 7;
    int end = beg + cnt[wid];
    int i = beg;
    for (; i + 16 <= end; i += 16) {
        unsigned p0 = pk2[i + eg], p1 = pk2[i + 4 + eg];
        unsigned p2 = pk2[i + 8 + eg], p3 = pk2[i + 12 + eg];
        float4 w0 = *((const float4*)(W1 + ((size_t)(p0 >> 15) * NN + (p0 & 0x7fffu)) * HH) + q);
        float4 w1 = *((const float4*)(W1 + ((size_t)(p1 >> 15) * NN + (p1 & 0x7fffu)) * HH) + q);
        float4 w2 = *((const float4*)(W1 + ((size_t)(p2 >> 15) * NN + (p2 & 0x7fffu)) * HH) + q);
        float4 w3 = *((const float4*)(W1 + ((size_t)(p3 >> 15) * NN + (p3 & 0x7fffu)) * HH) + q);
        acc4.x += (w0.x + w1.x) + (w2.x + w3.x);
        acc4.y += (w0.y + w1.y) + (w2.y + w3.y);
        acc4.z += (w0.z + w1.z) + (w2.z + w3.z);
        acc4.w += (w0.w + w1.w) + (w2.w + w3.w);
    }
    for (; i + 4 <= end; i += 4) {
        unsigned p = pk2[i + eg];
        float4 w = *((const float4*)(W1 + ((size_t)(p >> 15) * NN + (p & 0x7fffu)) * HH) + q);
        acc4.x += w.x; acc4.y += w.y; acc4.z += w.z; acc4.w += w.w;
    }
    // fold the 4 edge-subs (lane bits 4,5)
    acc4.x += __shfl_xor(acc4.x, 16); acc4.y += __shfl_xor(acc4.y, 16);
    acc4.z += __shfl_xor(acc4.z, 16); acc4.w += __shfl_xor(acc4.w, 16);
    acc4.x += __shfl_xor(acc4.x, 32); acc4.y += __shfl_xor(acc4.y, 32);
    acc4.z += __shfl_xor(acc4.z, 32); acc4.w += __shfl_xor(acc4.w, 32);
    // redistribute: lane l wants component (l&3) of quad (l>>2)
    int sl = lane >> 2;
    float cx = __shfl(acc4.x, sl), cy = __shfl(acc4.y, sl);
    float cz = __shfl(acc4.z, sl), cw = __shfl(acc4.w, sl);
    int comp = lane & 3;
    float acc = cx;
    if (comp == 1) acc = cy;
    if (comp == 2) acc = cz;
    if (comp == 3) acc = cw;
    // scalar tail (<= 3 edges)
    for (; i < end; ++i) {
        unsigned p = pk2[i];
        acc += W1[((size_t)(p >> 15) * NN + (p & 0x7fffu)) * HH + lane];
    }
    acc += root1[(size_t)wid * HH + lane] + bias1[lane];
    float hv = fmaxf(acc, 0.0f);
    h[(size_t)wid * HH + lane] = hv;
    // ---- root2 epilogue: lane k holds h[k]; root2 row k is 32B contiguous
    float4 ra = *(const float4*)(root2 + lane * CC);
    float4 rb = *(const float4*)(root2 + lane * CC + 4);
    float a0 = hv * ra.x, a1 = hv * ra.y, a2 = hv * ra.z, a3 = hv * ra.w;
    float a4 = hv * rb.x, a5 = hv * rb.y, a6 = hv * rb.z, a7 = hv * rb.w;
    #pragma unroll
    for (int m = 1; m < 8; m <<= 1) {
        a0 += __shfl_xor(a0, m); a1 += __shfl_xor(a1, m);
        a2 += __shfl_xor(a2, m); a3 += __shfl_xor(a3, m);
        a4 += __shfl_xor(a4, m); a5 += __shfl_xor(a5, m);
        a6 += __shfl_xor(a6, m); a7 += __shfl_xor(a7, m);
    }
    int c = lane & 7;
    float v = a0;
    if (c == 1) v = a1;  if (c == 2) v = a2;  if (c == 3) v = a3;
    if (c == 4) v = a4;  if (c == 5) v = a5;  if (c == 6) v = a6;
    if (c == 7) v = a7;
    v += __shfl_xor(v, 8);
    v += __shfl_xor(v, 16);
    v += __shfl_xor(v, 32);
    if (lane < 8) outr[(size_t)wid * CC + lane] = v;
}

// ---------------------------------------------------------------- layer 2
// r-group tiled (round-9 form): h row loaded once into registers per RT rels.
__global__ __launch_bounds__(256) void k_hrel(const float* __restrict__ h,
                                              const float* __restrict__ W2,
                                              float* __restrict__ hrel) {
    __shared__ float w2s[RT * HH * CC];   // 16 KB
    int r0 = blockIdx.y * RT;
    int tid = threadIdx.x;
    #pragma unroll
    for (int u = 0; u < RT * HH * CC / 256; u++)
        w2s[u * 256 + tid] = W2[(size_t)r0 * HH * CC + u * 256 + tid];
    __syncthreads();
    int n = blockIdx.x * 256 + tid;
    if (n >= NN) return;
    const float* hp = h + (size_t)n * HH;
    float4 hreg[HH / 4];
    #pragma unroll
    for (int k4 = 0; k4 < HH / 4; k4++) hreg[k4] = ((const float4*)hp)[k4];
    for (int rr = 0; rr < RT; rr++) {
        const float* w = w2s + rr * HH * CC;
        float acc[CC] = {0, 0, 0, 0, 0, 0, 0, 0};
        #pragma unroll
        for (int k4 = 0; k4 < HH / 4; k4++) {
            float4 hv = hreg[k4];
            int k = k4 * 4;
            #pragma unroll
            for (int c = 0; c < CC; c++) {
                acc[c] += hv.x * w[(k + 0) * CC + c] + hv.y * w[(k + 1) * CC + c]
                        + hv.z * w[(k + 2) * CC + c] + hv.w * w[(k + 3) * CC + c];
            }
        }
        float* op = hrel + ((size_t)(r0 + rr) * NN + n) * CC;
        *(float4*)(op)     = make_float4(acc[0], acc[1], acc[2], acc[3]);
        *(float4*)(op + 4) = make_float4(acc[4], acc[5], acc[6], acc[7]);
    }
}

// wave per dst node; 2 lanes per edge, float4 hrel reads (round-10 form).
__global__ __launch_bounds__(256) void k_gather2(const unsigned* __restrict__ pk2,
                                                 const int* __restrict__ cnt,
                                                 const float* __restrict__ hrel,
                                                 const float* __restrict__ outr,
                                                 const float* __restrict__ bias2,
                                                 float* __restrict__ out) {
    int wid = (blockIdx.x * 256 + threadIdx.x) >> 6;
    int lane = threadIdx.x & 63;
    if (wid >= NN) return;
    int eg = lane >> 1, half = lane & 1;
    float4 acc = make_float4(0.f, 0.f, 0.f, 0.f);
    int beg = wid << 7;
    int end = beg + cnt[wid];
    for (int i = beg + eg; i < end; i += 32) {
        unsigned p = pk2[i];
        float4 v = *((const float4*)(hrel + ((size_t)(p >> 15) * NN + (p & 0x7fffu)) * CC) + half);
        acc.x += v.x; acc.y += v.y; acc.z += v.z; acc.w += v.w;
    }
    #pragma unroll
    for (int m = 2; m < 64; m <<= 1) {
        acc.x += __shfl_xor(acc.x, m);
        acc.y += __shfl_xor(acc.y, m);
        acc.z += __shfl_xor(acc.z, m);
        acc.w += __shfl_xor(acc.w, m);
    }
    float4 o = *((const float4*)(outr + (size_t)wid * CC) + half);
    float4 b = *((const float4*)bias2 + half);
    float4 x;
    x.x = acc.x + o.x + b.x;
    x.y = acc.y + o.y + b.y;
    x.z = acc.z + o.z + b.z;
    x.w = acc.w + o.w + b.w;
    float m4 = fmaxf(fmaxf(x.x, x.y), fmaxf(x.z, x.w));
    float mm = fmaxf(m4, __shfl_xor(m4, 1));
    float e4 = expf(x.x - mm) + expf(x.y - mm) + expf(x.z - mm) + expf(x.w - mm);
    float ss = e4 + __shfl_xor(e4, 1);
    float l = mm + logf(ss);
    if (lane < 2) {
        float4 r = make_float4(x.x - l, x.y - l, x.z - l, x.w - l);
        *((float4*)(out + (size_t)wid * CC) + half) = r;
    }
}

extern "C" void kernel_launch(void* const* d_in, const int* in_sizes, int n_in,
                              void* d_out, int out_size, void* d_ws, size_t ws_size,
                              hipStream_t stream) {
    const int*   ei    = (const int*)d_in[0];    // [2, E]
    const int*   et    = (const int*)d_in[1];    // [E]
    const float* W1    = (const float*)d_in[3];  // [R, N, H]
    const float* root1 = (const float*)d_in[4];  // [N, H]
    const float* bias1 = (const float*)d_in[5];  // [H]
    const float* W2    = (const float*)d_in[6];  // [R, H, C]
    const float* root2 = (const float*)d_in[7];  // [H, C]
    const float* bias2 = (const float*)d_in[8];  // [C]
    float* out = (float*)d_out;

    char* base = (char*)d_ws;
    int*      cnt  = (int*)(base);                  // NN ints           [0, 80000)
    unsigned* pk2  = (unsigned*)(base + 80128);     // NN*CAP words      [80128, 10320128)
    float*    h    = (float*)(base + 10320128);     // NN*HH floats      [10320128, 15440128)
    float*    outr = (float*)(base + 15440128);     // NN*CC floats      [15440128, 16080128)
    float*    hrel = (float*)(base + 16080128);     // RR*NN*CC floats   [16080128, 36560128)

    k_zero   <<<(NN + 255) / 256, 256, 0, stream>>>(cnt);
    k_scatter<<<(EE / 4 + 255) / 256, 256, 0, stream>>>(ei, et, cnt, pk2);
    k_gather1<<<(NN * 64 + 255) / 256, 256, 0, stream>>>(pk2, cnt, W1, root1, bias1, root2, h, outr);
    k_hrel   <<<dim3((NN + 255) / 256, RR / RT), 256, 0, stream>>>(h, W2, hrel);
    // MEASUREMENT: k_gather2 is idempotent; run 4x so dur_us = base + 3*t_gather2.
    k_gather2<<<(NN * 64 + 255) / 256, 256, 0, stream>>>(pk2, cnt, hrel, outr, bias2, out);
    k_gather2<<<(NN * 64 + 255) / 256, 256, 0, stream>>>(pk2, cnt, hrel, outr, bias2, out);
    k_gather2<<<(NN * 64 + 255) / 256, 256, 0, stream>>>(pk2, cnt, hrel, outr, bias2, out);
    k_gather2<<<(NN * 64 + 255) / 256, 256, 0, stream>>>(pk2, cnt, hrel, outr, bias2, out);
}

// Round 15
// 130.621 us; speedup vs baseline: 1.2876x; 1.2876x over previous
//
#include <hip/hip_runtime.h>
#include <math.h>

#define NN 20000
#define RR 32
#define HH 64
#define CC 8
#define EE 640000
#define CAP 128   // bucket capacity per dst node; Poisson(32) max-degree ~57
#define RT 8      // relations per k_hrel block

// ---------------------------------------------------------------- bucket build
__global__ __launch_bounds__(256) void k_zero(int* __restrict__ cnt) {
    int i = blockIdx.x * 256 + threadIdx.x;
    if (i < NN) cnt[i] = 0;
}

// 1 edge per thread: max TLP to hide atomic-return latency.
__global__ __launch_bounds__(256) void k_scatter(const int* __restrict__ ei,
                                                 const int* __restrict__ et,
                                                 int* __restrict__ cnt,
                                                 unsigned* __restrict__ pk2) {
    int e = blockIdx.x * 256 + threadIdx.x;
    if (e >= EE) return;
    int d = ei[EE + e];
    unsigned p = (unsigned)ei[e] | ((unsigned)et[e] << 15);
    int s = atomicAdd(&cnt[d], 1);
    pk2[((size_t)d << 7) + s] = p;
}

// ---------------------------------------------------------------- layer 1
// (round-10 form, unchanged) wave per dst node; 16-lane x float4 per W1 row.
__global__ __launch_bounds__(256) void k_gather1(const unsigned* __restrict__ pk2,
                                                 const int* __restrict__ cnt,
                                                 const float* __restrict__ W1,
                                                 const float* __restrict__ root1,
                                                 const float* __restrict__ bias1,
                                                 const float* __restrict__ root2,
                                                 float* __restrict__ h,
                                                 float* __restrict__ outr) {
    int wid = (blockIdx.x * 256 + threadIdx.x) >> 6;
    int lane = threadIdx.x & 63;
    if (wid >= NN) return;
    const int eg = lane >> 4;   // which of 4 edges in a load-group
    const int q  = lane & 15;   // float4 index within the 64-float row
    float4 acc4 = make_float4(0.f, 0.f, 0.f, 0.f);
    int beg = wid << 7;
    int end = beg + cnt[wid];
    int i = beg;
    for (; i + 16 <= end; i += 16) {
        unsigned p0 = pk2[i + eg], p1 = pk2[i + 4 + eg];
        unsigned p2 = pk2[i + 8 + eg], p3 = pk2[i + 12 + eg];
        float4 w0 = *((const float4*)(W1 + ((size_t)(p0 >> 15) * NN + (p0 & 0x7fffu)) * HH) + q);
        float4 w1 = *((const float4*)(W1 + ((size_t)(p1 >> 15) * NN + (p1 & 0x7fffu)) * HH) + q);
        float4 w2 = *((const float4*)(W1 + ((size_t)(p2 >> 15) * NN + (p2 & 0x7fffu)) * HH) + q);
        float4 w3 = *((const float4*)(W1 + ((size_t)(p3 >> 15) * NN + (p3 & 0x7fffu)) * HH) + q);
        acc4.x += (w0.x + w1.x) + (w2.x + w3.x);
        acc4.y += (w0.y + w1.y) + (w2.y + w3.y);
        acc4.z += (w0.z + w1.z) + (w2.z + w3.z);
        acc4.w += (w0.w + w1.w) + (w2.w + w3.w);
    }
    for (; i + 4 <= end; i += 4) {
        unsigned p = pk2[i + eg];
        float4 w = *((const float4*)(W1 + ((size_t)(p >> 15) * NN + (p & 0x7fffu)) * HH) + q);
        acc4.x += w.x; acc4.y += w.y; acc4.z += w.z; acc4.w += w.w;
    }
    // fold the 4 edge-subs (lane bits 4,5)
    acc4.x += __shfl_xor(acc4.x, 16); acc4.y += __shfl_xor(acc4.y, 16);
    acc4.z += __shfl_xor(acc4.z, 16); acc4.w += __shfl_xor(acc4.w, 16);
    acc4.x += __shfl_xor(acc4.x, 32); acc4.y += __shfl_xor(acc4.y, 32);
    acc4.z += __shfl_xor(acc4.z, 32); acc4.w += __shfl_xor(acc4.w, 32);
    // redistribute: lane l wants component (l&3) of quad (l>>2)
    int sl = lane >> 2;
    float cx = __shfl(acc4.x, sl), cy = __shfl(acc4.y, sl);
    float cz = __shfl(acc4.z, sl), cw = __shfl(acc4.w, sl);
    int comp = lane & 3;
    float acc = cx;
    if (comp == 1) acc = cy;
    if (comp == 2) acc = cz;
    if (comp == 3) acc = cw;
    // scalar tail (<= 3 edges)
    for (; i < end; ++i) {
        unsigned p = pk2[i];
        acc += W1[((size_t)(p >> 15) * NN + (p & 0x7fffu)) * HH + lane];
    }
    acc += root1[(size_t)wid * HH + lane] + bias1[lane];
    float hv = fmaxf(acc, 0.0f);
    h[(size_t)wid * HH + lane] = hv;
    // ---- root2 epilogue: lane k holds h[k]; root2 row k is 32B contiguous
    float4 ra = *(const float4*)(root2 + lane * CC);
    float4 rb = *(const float4*)(root2 + lane * CC + 4);
    float a0 = hv * ra.x, a1 = hv * ra.y, a2 = hv * ra.z, a3 = hv * ra.w;
    float a4 = hv * rb.x, a5 = hv * rb.y, a6 = hv * rb.z, a7 = hv * rb.w;
    #pragma unroll
    for (int m = 1; m < 8; m <<= 1) {
        a0 += __shfl_xor(a0, m); a1 += __shfl_xor(a1, m);
        a2 += __shfl_xor(a2, m); a3 += __shfl_xor(a3, m);
        a4 += __shfl_xor(a4, m); a5 += __shfl_xor(a5, m);
        a6 += __shfl_xor(a6, m); a7 += __shfl_xor(a7, m);
    }
    int c = lane & 7;
    float v = a0;
    if (c == 1) v = a1;  if (c == 2) v = a2;  if (c == 3) v = a3;
    if (c == 4) v = a4;  if (c == 5) v = a5;  if (c == 6) v = a6;
    if (c == 7) v = a7;
    v += __shfl_xor(v, 8);
    v += __shfl_xor(v, 16);
    v += __shfl_xor(v, 32);
    if (lane < 8) outr[(size_t)wid * CC + lane] = v;
}

// ---------------------------------------------------------------- layer 2
// r-group tiled (round-9 form): h row loaded once into registers per RT rels.
__global__ __launch_bounds__(256) void k_hrel(const float* __restrict__ h,
                                              const float* __restrict__ W2,
                                              float* __restrict__ hrel) {
    __shared__ float w2s[RT * HH * CC];   // 16 KB
    int r0 = blockIdx.y * RT;
    int tid = threadIdx.x;
    #pragma unroll
    for (int u = 0; u < RT * HH * CC / 256; u++)
        w2s[u * 256 + tid] = W2[(size_t)r0 * HH * CC + u * 256 + tid];
    __syncthreads();
    int n = blockIdx.x * 256 + tid;
    if (n >= NN) return;
    const float* hp = h + (size_t)n * HH;
    float4 hreg[HH / 4];
    #pragma unroll
    for (int k4 = 0; k4 < HH / 4; k4++) hreg[k4] = ((const float4*)hp)[k4];
    for (int rr = 0; rr < RT; rr++) {
        const float* w = w2s + rr * HH * CC;
        float acc[CC] = {0, 0, 0, 0, 0, 0, 0, 0};
        #pragma unroll
        for (int k4 = 0; k4 < HH / 4; k4++) {
            float4 hv = hreg[k4];
            int k = k4 * 4;
            #pragma unroll
            for (int c = 0; c < CC; c++) {
                acc[c] += hv.x * w[(k + 0) * CC + c] + hv.y * w[(k + 1) * CC + c]
                        + hv.z * w[(k + 2) * CC + c] + hv.w * w[(k + 3) * CC + c];
            }
        }
        float* op = hrel + ((size_t)(r0 + rr) * NN + n) * CC;
        *(float4*)(op)     = make_float4(acc[0], acc[1], acc[2], acc[3]);
        *(float4*)(op + 4) = make_float4(acc[4], acc[5], acc[6], acc[7]);
    }
}

// wave per dst node; 2 lanes per edge, float4 hrel reads (round-10 form).
__global__ __launch_bounds__(256) void k_gather2(const unsigned* __restrict__ pk2,
                                                 const int* __restrict__ cnt,
                                                 const float* __restrict__ hrel,
                                                 const float* __restrict__ outr,
                                                 const float* __restrict__ bias2,
                                                 float* __restrict__ out) {
    int wid = (blockIdx.x * 256 + threadIdx.x) >> 6;
    int lane = threadIdx.x & 63;
    if (wid >= NN) return;
    int eg = lane >> 1, half = lane & 1;
    float4 acc = make_float4(0.f, 0.f, 0.f, 0.f);
    int beg = wid << 7;
    int end = beg + cnt[wid];
    for (int i = beg + eg; i < end; i += 32) {
        unsigned p = pk2[i];
        float4 v = *((const float4*)(hrel + ((size_t)(p >> 15) * NN + (p & 0x7fffu)) * CC) + half);
        acc.x += v.x; acc.y += v.y; acc.z += v.z; acc.w += v.w;
    }
    #pragma unroll
    for (int m = 2; m < 64; m <<= 1) {
        acc.x += __shfl_xor(acc.x, m);
        acc.y += __shfl_xor(acc.y, m);
        acc.z += __shfl_xor(acc.z, m);
        acc.w += __shfl_xor(acc.w, m);
    }
    float4 o = *((const float4*)(outr + (size_t)wid * CC) + half);
    float4 b = *((const float4*)bias2 + half);
    float4 x;
    x.x = acc.x + o.x + b.x;
    x.y = acc.y + o.y + b.y;
    x.z = acc.z + o.z + b.z;
    x.w = acc.w + o.w + b.w;
    float m4 = fmaxf(fmaxf(x.x, x.y), fmaxf(x.z, x.w));
    float mm = fmaxf(m4, __shfl_xor(m4, 1));
    float e4 = expf(x.x - mm) + expf(x.y - mm) + expf(x.z - mm) + expf(x.w - mm);
    float ss = e4 + __shfl_xor(e4, 1);
    float l = mm + logf(ss);
    if (lane < 2) {
        float4 r = make_float4(x.x - l, x.y - l, x.z - l, x.w - l);
        *((float4*)(out + (size_t)wid * CC) + half) = r;
    }
}

extern "C" void kernel_launch(void* const* d_in, const int* in_sizes, int n_in,
                              void* d_out, int out_size, void* d_ws, size_t ws_size,
                              hipStream_t stream) {
    const int*   ei    = (const int*)d_in[0];    // [2, E]
    const int*   et    = (const int*)d_in[1];    // [E]
    const float* W1    = (const float*)d_in[3];  // [R, N, H]
    const float* root1 = (const float*)d_in[4];  // [N, H]
    const float* bias1 = (const float*)d_in[5];  // [H]
    const float* W2    = (const float*)d_in[6];  // [R, H, C]
    const float* root2 = (const float*)d_in[7];  // [H, C]
    const float* bias2 = (const float*)d_in[8];  // [C]
    float* out = (float*)d_out;

    char* base = (char*)d_ws;
    int*      cnt  = (int*)(base);                  // NN ints           [0, 80000)
    unsigned* pk2  = (unsigned*)(base + 80128);     // NN*CAP words      [80128, 10320128)
    float*    h    = (float*)(base + 10320128);     // NN*HH floats      [10320128, 15440128)
    float*    outr = (float*)(base + 15440128);     // NN*CC floats      [15440128, 16080128)
    float*    hrel = (float*)(base + 16080128);     // RR*NN*CC floats   [16080128, 36560128)

    k_zero   <<<(NN + 255) / 256, 256, 0, stream>>>(cnt);
    k_scatter<<<(EE + 255) / 256, 256, 0, stream>>>(ei, et, cnt, pk2);
    k_gather1<<<(NN * 64 + 255) / 256, 256, 0, stream>>>(pk2, cnt, W1, root1, bias1, root2, h, outr);
    k_hrel   <<<dim3((NN + 255) / 256, RR / RT), 256, 0, stream>>>(h, W2, hrel);
    k_gather2<<<(NN * 64 + 255) / 256, 256, 0, stream>>>(pk2, cnt, hrel, outr, bias2, out);
}

// Round 16
// 124.710 us; speedup vs baseline: 1.3486x; 1.0474x over previous
//
#include <hip/hip_runtime.h>
#include <math.h>

#define NN 20000
#define RR 32
#define HH 64
#define CC 8
#define EE 640000
#define CAP 128   // bucket capacity per dst node; Poisson(32) max-degree ~57
#define RT 8      // relations per k_hrel block

// ---------------------------------------------------------------- bucket build
__global__ __launch_bounds__(256) void k_zero(int* __restrict__ cnt) {
    int i = blockIdx.x * 256 + threadIdx.x;
    if (i < NN) cnt[i] = 0;
}

// 4 edges per thread, int4 loads. All 4 atomics issued BEFORE any dependent
// store so their return latencies overlap (stores are fire-and-forget).
__global__ __launch_bounds__(256) void k_scatter(const int* __restrict__ ei,
                                                 const int* __restrict__ et,
                                                 int* __restrict__ cnt,
                                                 unsigned* __restrict__ pk2) {
    int e = (blockIdx.x * 256 + threadIdx.x) * 4;
    if (e >= EE) return;
    int4 sv = *(const int4*)(ei + e);
    int4 dv = *(const int4*)(ei + EE + e);
    int4 rv = *(const int4*)(et + e);
    int s0 = atomicAdd(&cnt[dv.x], 1);
    int s1 = atomicAdd(&cnt[dv.y], 1);
    int s2 = atomicAdd(&cnt[dv.z], 1);
    int s3 = atomicAdd(&cnt[dv.w], 1);
    pk2[((size_t)dv.x << 7) + s0] = (unsigned)sv.x | ((unsigned)rv.x << 15);
    pk2[((size_t)dv.y << 7) + s1] = (unsigned)sv.y | ((unsigned)rv.y << 15);
    pk2[((size_t)dv.z << 7) + s2] = (unsigned)sv.z | ((unsigned)rv.z << 15);
    pk2[((size_t)dv.w << 7) + s3] = (unsigned)sv.w | ((unsigned)rv.w << 15);
}

// ---------------------------------------------------------------- layer 1
// (round-10 form, unchanged) wave per dst node; 16-lane x float4 per W1 row.
__global__ __launch_bounds__(256) void k_gather1(const unsigned* __restrict__ pk2,
                                                 const int* __restrict__ cnt,
                                                 const float* __restrict__ W1,
                                                 const float* __restrict__ root1,
                                                 const float* __restrict__ bias1,
                                                 const float* __restrict__ root2,
                                                 float* __restrict__ h,
                                                 float* __restrict__ outr) {
    int wid = (blockIdx.x * 256 + threadIdx.x) >> 6;
    int lane = threadIdx.x & 63;
    if (wid >= NN) return;
    const int eg = lane >> 4;   // which of 4 edges in a load-group
    const int q  = lane & 15;   // float4 index within the 64-float row
    float4 acc4 = make_float4(0.f, 0.f, 0.f, 0.f);
    int beg = wid << 7;
    int end = beg + cnt[wid];
    int i = beg;
    for (; i + 16 <= end; i += 16) {
        unsigned p0 = pk2[i + eg], p1 = pk2[i + 4 + eg];
        unsigned p2 = pk2[i + 8 + eg], p3 = pk2[i + 12 + eg];
        float4 w0 = *((const float4*)(W1 + ((size_t)(p0 >> 15) * NN + (p0 & 0x7fffu)) * HH) + q);
        float4 w1 = *((const float4*)(W1 + ((size_t)(p1 >> 15) * NN + (p1 & 0x7fffu)) * HH) + q);
        float4 w2 = *((const float4*)(W1 + ((size_t)(p2 >> 15) * NN + (p2 & 0x7fffu)) * HH) + q);
        float4 w3 = *((const float4*)(W1 + ((size_t)(p3 >> 15) * NN + (p3 & 0x7fffu)) * HH) + q);
        acc4.x += (w0.x + w1.x) + (w2.x + w3.x);
        acc4.y += (w0.y + w1.y) + (w2.y + w3.y);
        acc4.z += (w0.z + w1.z) + (w2.z + w3.z);
        acc4.w += (w0.w + w1.w) + (w2.w + w3.w);
    }
    for (; i + 4 <= end; i += 4) {
        unsigned p = pk2[i + eg];
        float4 w = *((const float4*)(W1 + ((size_t)(p >> 15) * NN + (p & 0x7fffu)) * HH) + q);
        acc4.x += w.x; acc4.y += w.y; acc4.z += w.z; acc4.w += w.w;
    }
    // fold the 4 edge-subs (lane bits 4,5)
    acc4.x += __shfl_xor(acc4.x, 16); acc4.y += __shfl_xor(acc4.y, 16);
    acc4.z += __shfl_xor(acc4.z, 16); acc4.w += __shfl_xor(acc4.w, 16);
    acc4.x += __shfl_xor(acc4.x, 32); acc4.y += __shfl_xor(acc4.y, 32);
    acc4.z += __shfl_xor(acc4.z, 32); acc4.w += __shfl_xor(acc4.w, 32);
    // redistribute: lane l wants component (l&3) of quad (l>>2)
    int sl = lane >> 2;
    float cx = __shfl(acc4.x, sl), cy = __shfl(acc4.y, sl);
    float cz = __shfl(acc4.z, sl), cw = __shfl(acc4.w, sl);
    int comp = lane & 3;
    float acc = cx;
    if (comp == 1) acc = cy;
    if (comp == 2) acc = cz;
    if (comp == 3) acc = cw;
    // scalar tail (<= 3 edges)
    for (; i < end; ++i) {
        unsigned p = pk2[i];
        acc += W1[((size_t)(p >> 15) * NN + (p & 0x7fffu)) * HH + lane];
    }
    acc += root1[(size_t)wid * HH + lane] + bias1[lane];
    float hv = fmaxf(acc, 0.0f);
    h[(size_t)wid * HH + lane] = hv;
    // ---- root2 epilogue: lane k holds h[k]; root2 row k is 32B contiguous
    float4 ra = *(const float4*)(root2 + lane * CC);
    float4 rb = *(const float4*)(root2 + lane * CC + 4);
    float a0 = hv * ra.x, a1 = hv * ra.y, a2 = hv * ra.z, a3 = hv * ra.w;
    float a4 = hv * rb.x, a5 = hv * rb.y, a6 = hv * rb.z, a7 = hv * rb.w;
    #pragma unroll
    for (int m = 1; m < 8; m <<= 1) {
        a0 += __shfl_xor(a0, m); a1 += __shfl_xor(a1, m);
        a2 += __shfl_xor(a2, m); a3 += __shfl_xor(a3, m);
        a4 += __shfl_xor(a4, m); a5 += __shfl_xor(a5, m);
        a6 += __shfl_xor(a6, m); a7 += __shfl_xor(a7, m);
    }
    int c = lane & 7;
    float v = a0;
    if (c == 1) v = a1;  if (c == 2) v = a2;  if (c == 3) v = a3;
    if (c == 4) v = a4;  if (c == 5) v = a5;  if (c == 6) v = a6;
    if (c == 7) v = a7;
    v += __shfl_xor(v, 8);
    v += __shfl_xor(v, 16);
    v += __shfl_xor(v, 32);
    if (lane < 8) outr[(size_t)wid * CC + lane] = v;
}

// ---------------------------------------------------------------- layer 2
// r-group tiled (round-9 form): h row loaded once into registers per RT rels.
__global__ __launch_bounds__(256) void k_hrel(const float* __restrict__ h,
                                              const float* __restrict__ W2,
                                              float* __restrict__ hrel) {
    __shared__ float w2s[RT * HH * CC];   // 16 KB
    int r0 = blockIdx.y * RT;
    int tid = threadIdx.x;
    #pragma unroll
    for (int u = 0; u < RT * HH * CC / 256; u++)
        w2s[u * 256 + tid] = W2[(size_t)r0 * HH * CC + u * 256 + tid];
    __syncthreads();
    int n = blockIdx.x * 256 + tid;
    if (n >= NN) return;
    const float* hp = h + (size_t)n * HH;
    float4 hreg[HH / 4];
    #pragma unroll
    for (int k4 = 0; k4 < HH / 4; k4++) hreg[k4] = ((const float4*)hp)[k4];
    for (int rr = 0; rr < RT; rr++) {
        const float* w = w2s + rr * HH * CC;
        float acc[CC] = {0, 0, 0, 0, 0, 0, 0, 0};
        #pragma unroll
        for (int k4 = 0; k4 < HH / 4; k4++) {
            float4 hv = hreg[k4];
            int k = k4 * 4;
            #pragma unroll
            for (int c = 0; c < CC; c++) {
                acc[c] += hv.x * w[(k + 0) * CC + c] + hv.y * w[(k + 1) * CC + c]
                        + hv.z * w[(k + 2) * CC + c] + hv.w * w[(k + 3) * CC + c];
            }
        }
        float* op = hrel + ((size_t)(r0 + rr) * NN + n) * CC;
        *(float4*)(op)     = make_float4(acc[0], acc[1], acc[2], acc[3]);
        *(float4*)(op + 4) = make_float4(acc[4], acc[5], acc[6], acc[7]);
    }
}

// wave per dst node; 2 lanes per edge, float4 hrel reads (round-10 form).
__global__ __launch_bounds__(256) void k_gather2(const unsigned* __restrict__ pk2,
                                                 const int* __restrict__ cnt,
                                                 const float* __restrict__ hrel,
                                                 const float* __restrict__ outr,
                                                 const float* __restrict__ bias2,
                                                 float* __restrict__ out) {
    int wid = (blockIdx.x * 256 + threadIdx.x) >> 6;
    int lane = threadIdx.x & 63;
    if (wid >= NN) return;
    int eg = lane >> 1, half = lane & 1;
    float4 acc = make_float4(0.f, 0.f, 0.f, 0.f);
    int beg = wid << 7;
    int end = beg + cnt[wid];
    for (int i = beg + eg; i < end; i += 32) {
        unsigned p = pk2[i];
        float4 v = *((const float4*)(hrel + ((size_t)(p >> 15) * NN + (p & 0x7fffu)) * CC) + half);
        acc.x += v.x; acc.y += v.y; acc.z += v.z; acc.w += v.w;
    }
    #pragma unroll
    for (int m = 2; m < 64; m <<= 1) {
        acc.x += __shfl_xor(acc.x, m);
        acc.y += __shfl_xor(acc.y, m);
        acc.z += __shfl_xor(acc.z, m);
        acc.w += __shfl_xor(acc.w, m);
    }
    float4 o = *((const float4*)(outr + (size_t)wid * CC) + half);
    float4 b = *((const float4*)bias2 + half);
    float4 x;
    x.x = acc.x + o.x + b.x;
    x.y = acc.y + o.y + b.y;
    x.z = acc.z + o.z + b.z;
    x.w = acc.w + o.w + b.w;
    float m4 = fmaxf(fmaxf(x.x, x.y), fmaxf(x.z, x.w));
    float mm = fmaxf(m4, __shfl_xor(m4, 1));
    float e4 = expf(x.x - mm) + expf(x.y - mm) + expf(x.z - mm) + expf(x.w - mm);
    float ss = e4 + __shfl_xor(e4, 1);
    float l = mm + logf(ss);
    if (lane < 2) {
        float4 r = make_float4(x.x - l, x.y - l, x.z - l, x.w - l);
        *((float4*)(out + (size_t)wid * CC) + half) = r;
    }
}

extern "C" void kernel_launch(void* const* d_in, const int* in_sizes, int n_in,
                              void* d_out, int out_size, void* d_ws, size_t ws_size,
                              hipStream_t stream) {
    const int*   ei    = (const int*)d_in[0];    // [2, E]
    const int*   et    = (const int*)d_in[1];    // [E]
    const float* W1    = (const float*)d_in[3];  // [R, N, H]
    const float* root1 = (const float*)d_in[4];  // [N, H]
    const float* bias1 = (const float*)d_in[5];  // [H]
    const float* W2    = (const float*)d_in[6];  // [R, H, C]
    const float* root2 = (const float*)d_in[7];  // [H, C]
    const float* bias2 = (const float*)d_in[8];  // [C]
    float* out = (float*)d_out;

    char* base = (char*)d_ws;
    int*      cnt  = (int*)(base);                  // NN ints           [0, 80000)
    unsigned* pk2  = (unsigned*)(base + 80128);     // NN*CAP words      [80128, 10320128)
    float*    h    = (float*)(base + 10320128);     // NN*HH floats      [10320128, 15440128)
    float*    outr = (float*)(base + 15440128);     // NN*CC floats      [15440128, 16080128)
    float*    hrel = (float*)(base + 16080128);     // RR*NN*CC floats   [16080128, 36560128)

    k_zero   <<<(NN + 255) / 256, 256, 0, stream>>>(cnt);
    k_scatter<<<(EE / 4 + 255) / 256, 256, 0, stream>>>(ei, et, cnt, pk2);
    k_gather1<<<(NN * 64 + 255) / 256, 256, 0, stream>>>(pk2, cnt, W1, root1, bias1, root2, h, outr);
    k_hrel   <<<dim3((NN + 255) / 256, RR / RT), 256, 0, stream>>>(h, W2, hrel);
    k_gather2<<<(NN * 64 + 255) / 256, 256, 0, stream>>>(pk2, cnt, hrel, outr, bias2, out);
}